// Round 9
// baseline (63.689 us; speedup 1.0000x reference)
//
#include <hip/hip_runtime.h>
#include <math.h>

#define NROWS 8192
#define DIM   1024
#define GRID  64          // 64x64 cells over [0,1)^2
#define CELLW 0.015625f   // 1/64
#define LPR   16          // lanes cooperating per row in knn

__device__ __forceinline__ int cell_of(float v) {
    int c = (int)(v * 64.0f);
    return c < 0 ? 0 : (c > 63 ? 63 : c);
}

// Emulated numpy-f32 squared distance (identical to the passing R4-R8 kernels).
__device__ __forceinline__ float np_d2(float xi, float yi, float sqi,
                                       float xj, float yj) {
    float sqj = __fadd_rn(__fmul_rn(xj, xj), __fmul_rn(yj, yj));
    float G   = fmaf(yi, yj, __fmul_rn(xi, xj));
    return __fsub_rn(__fadd_rn(sqi, sqj), __fmul_rn(2.0f, G));
}

// Fused count + scan + scatter, one block (1024 threads), LDS-resident counts.
__global__ __launch_bounds__(1024) void build_grid_kernel(
    const float* __restrict__ coords,
    int* __restrict__ cellStart,     // 4097
    float4* __restrict__ sxyz) {     // 8192: (x, y, sq_np, idx_bits)

    __shared__ int lcnt[4096];
    __shared__ int wsum[16];
    const int t = threadIdx.x;

    for (int i = t; i < 4096; i += 1024) lcnt[i] = 0;
    __syncthreads();

    float2 pc[8]; int pcell[8];
#pragma unroll
    for (int k = 0; k < 8; ++k) {
        int i = t + 1024 * k;
        float2 c = ((const float2*)coords)[i];
        pc[k] = c;
        pcell[k] = cell_of(c.y) * GRID + cell_of(c.x);
        atomicAdd(&lcnt[pcell[k]], 1);
    }
    __syncthreads();

    // exclusive scan of 4096 counts, 4 cells per thread
    int c0 = lcnt[t*4+0], c1 = lcnt[t*4+1], c2 = lcnt[t*4+2], c3 = lcnt[t*4+3];
    int s1 = c0, s2 = c0 + c1, s3 = s2 + c2, s4 = s3 + c3;
    int lane = t & 63, wid = t >> 6;
    int inc = s4;
#pragma unroll
    for (int off = 1; off < 64; off <<= 1) {
        int o = __shfl_up(inc, off, 64);
        if (lane >= off) inc += o;
    }
    if (lane == 63) wsum[wid] = inc;
    __syncthreads();
    int wbase = 0;
    for (int w = 0; w < wid; ++w) wbase += wsum[w];
    int excl = wbase + inc - s4;

    cellStart[t*4+0] = excl;
    cellStart[t*4+1] = excl + s1;
    cellStart[t*4+2] = excl + s2;
    cellStart[t*4+3] = excl + s3;
    if (t == 1023) cellStart[4096] = excl + s4;
    lcnt[t*4+0] = excl;          // reuse as running cursor
    lcnt[t*4+1] = excl + s1;
    lcnt[t*4+2] = excl + s2;
    lcnt[t*4+3] = excl + s3;
    __syncthreads();

#pragma unroll
    for (int k = 0; k < 8; ++k) {
        int pos = atomicAdd(&lcnt[pcell[k]], 1);
        float x = pc[k].x, y = pc[k].y;
        float sq = __fadd_rn(__fmul_rn(x, x), __fmul_rn(y, y));
        sxyz[pos] = make_float4(x, y, sq, __int_as_float(t + 1024 * k));
    }
}

// Phase 1: exact top-10 of (np-f32 dist, index) per row. 16 lanes per row.
__global__ __launch_bounds__(256) void knn_kernel(
    const int* __restrict__ cellStart,   // 4097
    const float4* __restrict__ sxyz,     // 8192
    unsigned long long* __restrict__ chosen_ws) {

    const int sub = threadIdx.x & (LPR - 1);
    const int g   = (blockIdx.x * 256 + threadIdx.x) / LPR;   // sorted position

    const float4 me = sxyz[g];
    const float xi = me.x, yi = me.y, sqi = me.z;
    const int row = __float_as_int(me.w);
    const int cx = cell_of(xi), cy = cell_of(yi);

    unsigned long long best[10], merged[10];
    int C = 2;
    while (true) {
#pragma unroll
        for (int s = 0; s < 10; ++s) best[s] = ~0ULL;
        int x0 = max(0, cx - C), x1 = min(GRID - 1, cx + C);
        int y0 = max(0, cy - C), y1 = min(GRID - 1, cy + C);
        for (int yy = y0; yy <= y1; ++yy) {
            int s = cellStart[yy * GRID + x0];
            int e = cellStart[yy * GRID + x1 + 1];
            for (int t = s + sub; t < e; t += LPR) {
                float4 c = sxyz[t];
                float d2  = __fsub_rn(__fadd_rn(sqi, c.z),
                                      __fmul_rn(2.0f, fmaf(yi, c.y, __fmul_rn(xi, c.x))));
                float dst = __fsqrt_rn(fmaxf(d2, 0.0f));
                unsigned long long key =
                    ((unsigned long long)__float_as_uint(dst) << 32)
                    | (unsigned int)__float_as_int(c.w);
                if (key < best[9]) {
                    best[9] = key;
#pragma unroll
                    for (int ss = 9; ss >= 1; --ss) {
                        unsigned long long a = best[ss - 1], b = best[ss];
                        unsigned long long lo = a < b ? a : b;
                        unsigned long long hi = a < b ? b : a;
                        best[ss - 1] = lo;
                        best[ss]     = hi;
                    }
                }
            }
        }
        // merge 16 sorted lists: 10 rounds of head-min; winner pops its head
#pragma unroll
        for (int r = 0; r < 10; ++r) {
            unsigned long long mn = best[0];
#pragma unroll
            for (int off = 1; off < LPR; off <<= 1) {
                unsigned long long o = __shfl_xor(mn, off, 64);
                mn = (o < mn) ? o : mn;
            }
            if (best[0] == mn) {
#pragma unroll
                for (int ss = 0; ss < 9; ++ss) best[ss] = best[ss + 1];
                best[9] = ~0ULL;
            }
            merged[r] = mn;
        }
        bool done = false;
        if (merged[9] != ~0ULL) {
            float d9 = __uint_as_float((unsigned int)(merged[9] >> 32));
            if (d9 + 1.0e-3f <= (float)C * CELLW) done = true;
        }
        if (done || C >= GRID) break;
        C <<= 1; if (C > GRID) C = GRID;
    }

    if (sub == 0) {
        unsigned long long* o = chosen_ws + (size_t)row * 10;
#pragma unroll
        for (int r = 0; r < 10; ++r) o[r] = merged[r];
    }
}

// Phase 2 (fused): per-row block computes 10 neighbor dots + neighbor norms
// (q = b.b rides along in the same loop, zero extra loads) + self-dot, then
// wave 0 runs the blend + MLP. Bit-identical arithmetic to the R5-R8 chain:
// norms via same lane-partition butterfly, blend/MLP code verbatim.
__global__ __launch_bounds__(256) void gather_final_kernel(
    const float* __restrict__ h0,
    const float* __restrict__ coords,
    const unsigned long long* __restrict__ chosen_ws,
    const float4* __restrict__ sxyz,
    const float* __restrict__ W1, const float* __restrict__ b1,
    const float* __restrict__ W2, const float* __restrict__ b2,
    float* __restrict__ out) {

    __shared__ float2 pq[11];   // (p = a.b, q = b.b) per slot; slot10 = self

    const int widx = threadIdx.x >> 6;
    const int lane = threadIdx.x & 63;
    const int bid  = blockIdx.x;
    const int g    = (bid & 7) * (NROWS / 8) + (bid >> 3);  // XCD-chunked
    const int row  = __float_as_int(sxyz[g].w);

    const float4* hi = (const float4*)(h0 + (size_t)row * DIM);
    float4 a[4];
#pragma unroll
    for (int t = 0; t < 4; ++t) a[t] = hi[lane + 64 * t];

    const unsigned long long* ch = chosen_ws + (size_t)row * 10;

    for (int s = widx; s <= 10; s += 4) {
        float p = 0.f, q = 0.f;
        if (s == 10) {
#pragma unroll
            for (int t = 0; t < 4; ++t)
                p += a[t].x * a[t].x + a[t].y * a[t].y + a[t].z * a[t].z + a[t].w * a[t].w;
            q = p;
        } else {
            int j = (int)(ch[s] & 0xFFFFFFFFu);
            const float4* hj = (const float4*)(h0 + (size_t)j * DIM);
#pragma unroll
            for (int t = 0; t < 4; ++t) {
                float4 b = hj[lane + 64 * t];
                p += a[t].x * b.x + a[t].y * b.y + a[t].z * b.z + a[t].w * b.w;
                q += b.x * b.x + b.y * b.y + b.z * b.z + b.w * b.w;
            }
        }
#pragma unroll
        for (int off = 1; off < 64; off <<= 1) {
            p += __shfl_xor(p, off, 64);
            q += __shfl_xor(q, off, 64);
        }
        if (lane == 0) pq[s] = make_float2(p, q);
    }
    __syncthreads();

    if (widx != 0) return;

    // ---- wave 0: blend flags + sim/sw + MLP (verbatim from R5-R8) ----
    const float2 ci = ((const float2*)coords)[row];
    const float xi = ci.x, yi = ci.y;
    const float sqi = __fadd_rn(__fmul_rn(xi, xi), __fmul_rn(yi, yi));

    unsigned long long chosen[10];
#pragma unroll
    for (int r = 0; r < 10; ++r) chosen[r] = ch[r];

    auto clamped_d2 = [&](unsigned long long key) -> float {
        int j = (int)(key & 0xFFFFFFFFu);
        float2 cj = ((const float2*)coords)[j];
        return fmaxf(np_d2(xi, yi, sqi, cj.x, cj.y), 0.0f);
    };
    const float m0 = clamped_d2(chosen[0]);
    const float m1 = clamped_d2(chosen[1]);
    const float m2 = clamped_d2(chosen[2]);
    const float m8 = clamped_d2(chosen[8]);
    const float m9 = clamped_d2(chosen[9]);

    const float WIN = 2.0e-6f;
    const bool fpair = (m1 - m0) <= WIN;
    const bool ftri  = fpair && ((m2 - m0) <= WIN);
    const bool f89   = (m9 - m8) <= WIN;

    float wd[3];
    wd[0] = ftri ? (1.f / 3.f) : (fpair ? 0.5f : 1.0f);
    wd[1] = ftri ? (1.f / 3.f) : (fpair ? 0.5f : 0.0f);
    wd[2] = ftri ? (1.f / 3.f) : 0.0f;
    const float wc0 = f89 ? 0.5f : 1.0f;
    const float wc1 = f89 ? 0.5f : 0.0f;

    const float ni = fmaxf(sqrtf(pq[10].x), 1e-8f);

    float sim[10], sw[10];
#pragma unroll
    for (int r = 0; r < 10; ++r) {
        float dst = __uint_as_float((unsigned int)(chosen[r] >> 32));
        float nj  = fmaxf(sqrtf(pq[r].y), 1e-8f);
        sim[r] = pq[r].x / (ni * nj);
        sw[r]  = expf(__fdiv_rn(-dst, 0.05f));
    }

    float Ssim = 0.f, Ssw = 0.f;
#pragma unroll
    for (int r = 0; r < 9; ++r) { Ssim += sim[r]; Ssw += sw[r]; }

    const float w1a = W1[lane], w1b = W1[64 + lane];
    const float b1l = b1[lane], w2l = W2[lane], b2s = b2[0];

    float outacc = 0.f;
#pragma unroll
    for (int d = 0; d < 3; ++d) {
#pragma unroll
        for (int c = 0; c < 2; ++c) {
            float wgt = wd[d] * (c ? wc1 : wc0);
            float simsum = Ssim - sim[d] + (c ? (sim[9] - sim[8]) : 0.f);
            float swsum  = Ssw  - sw[d]  + (c ? (sw[9]  - sw[8])  : 0.f);
            float di0 = simsum * 0.125f;
            float di1 = swsum  * 0.125f;
            float hm = fmaxf(di0 * w1a + di1 * w1b + b1l, 0.f);
            float v  = hm * w2l;
#pragma unroll
            for (int off = 1; off < 64; off <<= 1) v += __shfl_xor(v, off, 64);
            float z = v + b2s;
            outacc += wgt * (1.f / (1.f + expf(-z)));
        }
    }

    if (lane == 0) out[row] = outacc;
}

extern "C" void kernel_launch(void* const* d_in, const int* in_sizes, int n_in,
                              void* d_out, int out_size, void* d_ws, size_t ws_size,
                              hipStream_t stream) {
    const float* h0     = (const float*)d_in[0];
    const float* coords = (const float*)d_in[1];
    const float* W1     = (const float*)d_in[2];
    const float* b1     = (const float*)d_in[3];
    const float* W2     = (const float*)d_in[4];
    const float* b2     = (const float*)d_in[5];
    float* out = (float*)d_out;

    // ws layout
    char* ws = (char*)d_ws;
    unsigned long long* chosen_ws = (unsigned long long*)(ws);    // 655360 B
    float4* sxyz      = (float4*)(ws + 1015808);                  // 131072 B (16B aligned)
    int*    cellStart = (int*)(ws + 1146880);                     //  16388 B

    build_grid_kernel  <<<1, 1024, 0, stream>>>(coords, cellStart, sxyz);
    knn_kernel         <<<NROWS * LPR / 256, 256, 0, stream>>>(cellStart, sxyz, chosen_ws);
    gather_final_kernel<<<NROWS, 256, 0, stream>>>(h0, coords, chosen_ws, sxyz,
                                                   W1, b1, W2, b2, out);
}

// Round 10
// 58.366 us; speedup vs baseline: 1.0912x; 1.0912x over previous
//
#include <hip/hip_runtime.h>
#include <math.h>

#define NROWS 8192
#define DIM   1024
#define GRID  64          // 64x64 cells over [0,1)^2
#define CELLW 0.015625f   // 1/64
#define LPR   16          // lanes cooperating per row in knn

__device__ __forceinline__ int cell_of(float v) {
    int c = (int)(v * 64.0f);
    return c < 0 ? 0 : (c > 63 ? 63 : c);
}

// Emulated numpy-f32 squared distance (identical to the passing R4-R9 kernels).
__device__ __forceinline__ float np_d2(float xi, float yi, float sqi,
                                       float xj, float yj) {
    float sqj = __fadd_rn(__fmul_rn(xj, xj), __fmul_rn(yj, yj));
    float G   = fmaf(yi, yj, __fmul_rn(xi, xj));
    return __fsub_rn(__fadd_rn(sqi, sqj), __fmul_rn(2.0f, G));
}

// Fused count + scan + scatter, one block (1024 threads), LDS-resident counts.
__global__ __launch_bounds__(1024) void build_grid_kernel(
    const float* __restrict__ coords,
    int* __restrict__ cellStart,     // 4097
    float4* __restrict__ sxyz) {     // 8192: (x, y, sq_np, idx_bits)

    __shared__ int lcnt[4096];
    __shared__ int wsum[16];
    const int t = threadIdx.x;

    for (int i = t; i < 4096; i += 1024) lcnt[i] = 0;
    __syncthreads();

    float2 pc[8]; int pcell[8];
#pragma unroll
    for (int k = 0; k < 8; ++k) {
        int i = t + 1024 * k;
        float2 c = ((const float2*)coords)[i];
        pc[k] = c;
        pcell[k] = cell_of(c.y) * GRID + cell_of(c.x);
        atomicAdd(&lcnt[pcell[k]], 1);
    }
    __syncthreads();

    // exclusive scan of 4096 counts, 4 cells per thread
    int c0 = lcnt[t*4+0], c1 = lcnt[t*4+1], c2 = lcnt[t*4+2], c3 = lcnt[t*4+3];
    int s1 = c0, s2 = c0 + c1, s3 = s2 + c2, s4 = s3 + c3;
    int lane = t & 63, wid = t >> 6;
    int inc = s4;
#pragma unroll
    for (int off = 1; off < 64; off <<= 1) {
        int o = __shfl_up(inc, off, 64);
        if (lane >= off) inc += o;
    }
    if (lane == 63) wsum[wid] = inc;
    __syncthreads();
    int wbase = 0;
    for (int w = 0; w < wid; ++w) wbase += wsum[w];
    int excl = wbase + inc - s4;

    cellStart[t*4+0] = excl;
    cellStart[t*4+1] = excl + s1;
    cellStart[t*4+2] = excl + s2;
    cellStart[t*4+3] = excl + s3;
    if (t == 1023) cellStart[4096] = excl + s4;
    lcnt[t*4+0] = excl;          // reuse as running cursor
    lcnt[t*4+1] = excl + s1;
    lcnt[t*4+2] = excl + s2;
    lcnt[t*4+3] = excl + s3;
    __syncthreads();

#pragma unroll
    for (int k = 0; k < 8; ++k) {
        int pos = atomicAdd(&lcnt[pcell[k]], 1);
        float x = pc[k].x, y = pc[k].y;
        float sq = __fadd_rn(__fmul_rn(x, x), __fmul_rn(y, y));
        sxyz[pos] = make_float4(x, y, sq, __int_as_float(t + 1024 * k));
    }
}

// Phase 1: exact top-10 of (np-f32 dist, index) per row. 16 lanes per row.
__global__ __launch_bounds__(256) void knn_kernel(
    const int* __restrict__ cellStart,   // 4097
    const float4* __restrict__ sxyz,     // 8192
    unsigned long long* __restrict__ chosen_ws) {

    const int sub = threadIdx.x & (LPR - 1);
    const int g   = (blockIdx.x * 256 + threadIdx.x) / LPR;   // sorted position

    const float4 me = sxyz[g];
    const float xi = me.x, yi = me.y, sqi = me.z;
    const int row = __float_as_int(me.w);
    const int cx = cell_of(xi), cy = cell_of(yi);

    unsigned long long best[10], merged[10];
    int C = 2;
    while (true) {
#pragma unroll
        for (int s = 0; s < 10; ++s) best[s] = ~0ULL;
        int x0 = max(0, cx - C), x1 = min(GRID - 1, cx + C);
        int y0 = max(0, cy - C), y1 = min(GRID - 1, cy + C);
        for (int yy = y0; yy <= y1; ++yy) {
            int s = cellStart[yy * GRID + x0];
            int e = cellStart[yy * GRID + x1 + 1];
            for (int t = s + sub; t < e; t += LPR) {
                float4 c = sxyz[t];
                float d2  = __fsub_rn(__fadd_rn(sqi, c.z),
                                      __fmul_rn(2.0f, fmaf(yi, c.y, __fmul_rn(xi, c.x))));
                float dst = __fsqrt_rn(fmaxf(d2, 0.0f));
                unsigned long long key =
                    ((unsigned long long)__float_as_uint(dst) << 32)
                    | (unsigned int)__float_as_int(c.w);
                if (key < best[9]) {
                    best[9] = key;
#pragma unroll
                    for (int ss = 9; ss >= 1; --ss) {
                        unsigned long long a = best[ss - 1], b = best[ss];
                        unsigned long long lo = a < b ? a : b;
                        unsigned long long hi = a < b ? b : a;
                        best[ss - 1] = lo;
                        best[ss]     = hi;
                    }
                }
            }
        }
        // merge 16 sorted lists: 10 rounds of head-min; winner pops its head
#pragma unroll
        for (int r = 0; r < 10; ++r) {
            unsigned long long mn = best[0];
#pragma unroll
            for (int off = 1; off < LPR; off <<= 1) {
                unsigned long long o = __shfl_xor(mn, off, 64);
                mn = (o < mn) ? o : mn;
            }
            if (best[0] == mn) {
#pragma unroll
                for (int ss = 0; ss < 9; ++ss) best[ss] = best[ss + 1];
                best[9] = ~0ULL;
            }
            merged[r] = mn;
        }
        bool done = false;
        if (merged[9] != ~0ULL) {
            float d9 = __uint_as_float((unsigned int)(merged[9] >> 32));
            if (d9 + 1.0e-3f <= (float)C * CELLW) done = true;
        }
        if (done || C >= GRID) break;
        C <<= 1; if (C > GRID) C = GRID;
    }

    if (sub == 0) {
        unsigned long long* o = chosen_ws + (size_t)row * 10;
#pragma unroll
        for (int r = 0; r < 10; ++r) o[r] = merged[r];
    }
}

// Phase 2 (fused, wave-per-row): slot-batched loads (10 independent float4
// loads per dim-chunk), p/q in registers, one butterfly pass per row, then
// the same wave runs blend + MLP. No LDS, no __syncthreads, no idle waves.
__global__ __launch_bounds__(256) void gather_final_kernel(
    const float* __restrict__ h0,
    const float* __restrict__ coords,
    const unsigned long long* __restrict__ chosen_ws,
    const float4* __restrict__ sxyz,
    const float* __restrict__ W1, const float* __restrict__ b1,
    const float* __restrict__ W2, const float* __restrict__ b2,
    float* __restrict__ out) {

    const int wid  = threadIdx.x >> 6;
    const int lane = threadIdx.x & 63;
    const int bid  = blockIdx.x;
    const int grp  = (bid & 7) * (gridDim.x / 8) + (bid >> 3);  // XCD-chunked
    const int g    = grp * 4 + wid;                             // sorted position
    const int row  = __float_as_int(sxyz[g].w);

    const unsigned long long* ch = chosen_ws + (size_t)row * 10;
    unsigned long long chosen[10];
    int jidx[10];
#pragma unroll
    for (int r = 0; r < 10; ++r) {
        chosen[r] = ch[r];
        jidx[r]   = (int)(chosen[r] & 0xFFFFFFFFu);
    }

    const float4* hi = (const float4*)(h0 + (size_t)row * DIM);

    float p[11];    // p[10] = self dot (a.a)
    float q[10];
#pragma unroll
    for (int s = 0; s < 11; ++s) p[s] = 0.f;
#pragma unroll
    for (int s = 0; s < 10; ++s) q[s] = 0.f;

    for (int t = 0; t < 4; ++t) {
        float4 av = hi[lane + 64 * t];
        p[10] += av.x * av.x + av.y * av.y + av.z * av.z + av.w * av.w;
#pragma unroll
        for (int s = 0; s < 10; ++s) {
            float4 b = ((const float4*)(h0 + (size_t)jidx[s] * DIM))[lane + 64 * t];
            p[s] += av.x * b.x + av.y * b.y + av.z * b.z + av.w * b.w;
            q[s] += b.x * b.x + b.y * b.y + b.z * b.z + b.w * b.w;
        }
    }

    // one butterfly pass per row (all lanes end with the sums)
#pragma unroll
    for (int s = 0; s < 11; ++s) {
        float v = p[s];
#pragma unroll
        for (int off = 1; off < 64; off <<= 1) v += __shfl_xor(v, off, 64);
        p[s] = v;
    }
#pragma unroll
    for (int s = 0; s < 10; ++s) {
        float v = q[s];
#pragma unroll
        for (int off = 1; off < 64; off <<= 1) v += __shfl_xor(v, off, 64);
        q[s] = v;
    }

    // ---- blend flags + sim/sw + MLP (verbatim logic from R5-R9) ----
    const float2 ci = ((const float2*)coords)[row];
    const float xi = ci.x, yi = ci.y;
    const float sqi = __fadd_rn(__fmul_rn(xi, xi), __fmul_rn(yi, yi));

    auto clamped_d2 = [&](unsigned long long key) -> float {
        int j = (int)(key & 0xFFFFFFFFu);
        float2 cj = ((const float2*)coords)[j];
        return fmaxf(np_d2(xi, yi, sqi, cj.x, cj.y), 0.0f);
    };
    const float m0 = clamped_d2(chosen[0]);
    const float m1 = clamped_d2(chosen[1]);
    const float m2 = clamped_d2(chosen[2]);
    const float m8 = clamped_d2(chosen[8]);
    const float m9 = clamped_d2(chosen[9]);

    const float WIN = 2.0e-6f;
    const bool fpair = (m1 - m0) <= WIN;
    const bool ftri  = fpair && ((m2 - m0) <= WIN);
    const bool f89   = (m9 - m8) <= WIN;

    float wd[3];
    wd[0] = ftri ? (1.f / 3.f) : (fpair ? 0.5f : 1.0f);
    wd[1] = ftri ? (1.f / 3.f) : (fpair ? 0.5f : 0.0f);
    wd[2] = ftri ? (1.f / 3.f) : 0.0f;
    const float wc0 = f89 ? 0.5f : 1.0f;
    const float wc1 = f89 ? 0.5f : 0.0f;

    const float ni = fmaxf(sqrtf(p[10]), 1e-8f);

    float sim[10], sw[10];
#pragma unroll
    for (int r = 0; r < 10; ++r) {
        float dst = __uint_as_float((unsigned int)(chosen[r] >> 32));
        float nj  = fmaxf(sqrtf(q[r]), 1e-8f);
        sim[r] = p[r] / (ni * nj);
        sw[r]  = expf(__fdiv_rn(-dst, 0.05f));
    }

    float Ssim = 0.f, Ssw = 0.f;
#pragma unroll
    for (int r = 0; r < 9; ++r) { Ssim += sim[r]; Ssw += sw[r]; }

    const float w1a = W1[lane], w1b = W1[64 + lane];
    const float b1l = b1[lane], w2l = W2[lane], b2s = b2[0];

    float outacc = 0.f;
#pragma unroll
    for (int d = 0; d < 3; ++d) {
#pragma unroll
        for (int c = 0; c < 2; ++c) {
            float wgt = wd[d] * (c ? wc1 : wc0);
            float simsum = Ssim - sim[d] + (c ? (sim[9] - sim[8]) : 0.f);
            float swsum  = Ssw  - sw[d]  + (c ? (sw[9]  - sw[8])  : 0.f);
            float di0 = simsum * 0.125f;
            float di1 = swsum  * 0.125f;
            float hm = fmaxf(di0 * w1a + di1 * w1b + b1l, 0.f);
            float v  = hm * w2l;
#pragma unroll
            for (int off = 1; off < 64; off <<= 1) v += __shfl_xor(v, off, 64);
            float z = v + b2s;
            outacc += wgt * (1.f / (1.f + expf(-z)));
        }
    }

    if (lane == 0) out[row] = outacc;
}

extern "C" void kernel_launch(void* const* d_in, const int* in_sizes, int n_in,
                              void* d_out, int out_size, void* d_ws, size_t ws_size,
                              hipStream_t stream) {
    const float* h0     = (const float*)d_in[0];
    const float* coords = (const float*)d_in[1];
    const float* W1     = (const float*)d_in[2];
    const float* b1     = (const float*)d_in[3];
    const float* W2     = (const float*)d_in[4];
    const float* b2     = (const float*)d_in[5];
    float* out = (float*)d_out;

    // ws layout
    char* ws = (char*)d_ws;
    unsigned long long* chosen_ws = (unsigned long long*)(ws);    // 655360 B
    float4* sxyz      = (float4*)(ws + 1015808);                  // 131072 B (16B aligned)
    int*    cellStart = (int*)(ws + 1146880);                     //  16388 B

    build_grid_kernel  <<<1, 1024, 0, stream>>>(coords, cellStart, sxyz);
    knn_kernel         <<<NROWS * LPR / 256, 256, 0, stream>>>(cellStart, sxyz, chosen_ws);
    gather_final_kernel<<<NROWS / 4, 256, 0, stream>>>(h0, coords, chosen_ws, sxyz,
                                                       W1, b1, W2, b2, out);
}